// Round 2
// baseline (527.955 us; speedup 1.0000x reference)
//
#include <hip/hip_runtime.h>
#include <math.h>

#define D_MODEL 1024
#define NUM_EXPERTS 8
#define TOP_K 2
#define LANES_PER_TOKEN 8        // L: 8 lanes cooperate on one token
#define GROUPS_PER_WAVE 8        // 64 / L
#define TOKENS_PER_GROUP 2       // each W register feeds 2 tokens' FMAs
#define TOKENS_PER_WAVE (GROUPS_PER_WAVE * TOKENS_PER_GROUP)   // 16
#define WAVES_PER_BLOCK 4
#define TOKENS_PER_BLOCK (TOKENS_PER_WAVE * WAVES_PER_BLOCK)   // 64

typedef float f4 __attribute__((ext_vector_type(4)));

// One DPP-permute + add (pure VALU, no LDS pipe).
template<int CTRL>
__device__ __forceinline__ float dpp_add(float v) {
    int s = __builtin_amdgcn_update_dpp(0, __builtin_bit_cast(int, v),
                                        CTRL, 0xF, 0xF, true);
    return v + __builtin_bit_cast(float, s);
}

__device__ __forceinline__ float dot4(f4 a, f4 b) {
    return a.x * b.x + a.y * b.y + a.z * b.z + a.w * b.w;
}

// Key change vs round 0: TOKENS_PER_GROUP=2. Each ds_read_b128 of W delivers
// 128B broadcast to 8 groups; reads/token is 32 regardless of lanes-per-token,
// so the only way to cut the LDS pipe (20.5us/CU, tied with HBM 20.8us/CU) is
// to reuse each wv register across 2 tokens -> 16 reads/token, ~10us/CU LDS.
// Grid drops to 512 blocks (8 waves/CU resident), so x loads are chunk-level
// double-buffered: chunk c+1's 16 loads (4KB/lane-group) issue before chunk
// c's compute, keeping ~16KB/wave of HBM traffic in flight.
__global__ __launch_bounds__(256) void gating_kernel(
    const float* __restrict__ x, const float* __restrict__ W,
    const float* __restrict__ b, float* __restrict__ out_w,
    float* __restrict__ out_idx, int n_tokens)
{
    __shared__ float Wlds[NUM_EXPERTS * D_MODEL];  // 32 KB

    const int wave = threadIdx.x >> 6;
    const int lane = threadIdx.x & 63;
    const int g = lane >> 3;
    const int l = lane & 7;
    const int base = blockIdx.x * TOKENS_PER_BLOCK + wave * TOKENS_PER_WAVE;
    const int t0 = base + g;       // tt=0: tokens base..base+7 across groups
    const int t1 = base + 8 + g;   // tt=1: tokens base+8..base+15

    // Clamp for OOB safety (stores are guarded); n_tokens%64==0 in practice.
    const int t0c = t0 < n_tokens ? t0 : 0;
    const int t1c = t1 < n_tokens ? t1 : 0;
    const f4* xg0 = (const f4*)x + (size_t)t0c * (D_MODEL / 4) + l;
    const f4* xg1 = (const f4*)x + (size_t)t1c * (D_MODEL / 4) + l;

    // Issue chunk-0 x loads BEFORE staging W so HBM latency overlaps the stage.
    f4 xa[2][TOKENS_PER_GROUP][8];
#pragma unroll
    for (int kk = 0; kk < 8; ++kk) {
        xa[0][0][kk] = __builtin_nontemporal_load(xg0 + kk * 8);
        xa[0][1][kk] = __builtin_nontemporal_load(xg1 + kk * 8);
    }

    {   // stage W: 2048 float4 across 256 threads
        const f4* Wg = (const f4*)W;
        f4* Ws = (f4*)Wlds;
        const int tid = threadIdx.x;
#pragma unroll
        for (int i = 0; i < (NUM_EXPERTS * D_MODEL / 4) / 256; ++i)
            Ws[tid + i * 256] = Wg[tid + i * 256];
    }
    __syncthreads();

    const f4* Wl = (const f4*)Wlds + l;  // +e*256 + (c*8+kk)*8 per read

    float acc[TOKENS_PER_GROUP][NUM_EXPERTS];
#pragma unroll
    for (int tt = 0; tt < TOKENS_PER_GROUP; ++tt)
#pragma unroll
        for (int e = 0; e < NUM_EXPERTS; ++e) acc[tt][e] = 0.f;

#pragma unroll
    for (int c = 0; c < 4; ++c) {
        const int cur = c & 1, nxt = cur ^ 1;  // compile-time after unroll
        if (c < 3) {  // prefetch chunk c+1 while computing chunk c
#pragma unroll
            for (int kk = 0; kk < 8; ++kk) {
                xa[nxt][0][kk] =
                    __builtin_nontemporal_load(xg0 + ((c + 1) * 8 + kk) * 8);
                xa[nxt][1][kk] =
                    __builtin_nontemporal_load(xg1 + ((c + 1) * 8 + kk) * 8);
            }
        }
#pragma unroll
        for (int e = 0; e < NUM_EXPERTS; ++e) {
            float s0 = acc[0][e];
            float s1 = acc[1][e];
#pragma unroll
            for (int kk = 0; kk < 8; ++kk) {
                const f4 wv = Wl[e * 256 + (c * 8 + kk) * 8];  // 128B/8 lanes,
                s0 += dot4(xa[cur][0][kk], wv);                // broadcast x8
                s1 += dot4(xa[cur][1][kk], wv);                // reused 2 tokens
            }
            acc[0][e] = s0;
            acc[1][e] = s1;
        }
    }

    const f4 blo = ((const f4*)b)[0];
    const f4 bhi = ((const f4*)b)[1];
    const float bb[NUM_EXPERTS] = {blo.x, blo.y, blo.z, blo.w,
                                   bhi.x, bhi.y, bhi.z, bhi.w};

#pragma unroll
    for (int tt = 0; tt < TOKENS_PER_GROUP; ++tt) {
        const int token = base + tt * 8 + g;
        if (token >= n_tokens) continue;  // whole 8-lane group masks together

        // 8-lane group reduce: 3 DPP steps, XOR/mirror pairings -> all 8 lanes
        // get bit-identical sums (commutative adds, same grouping), so the
        // weight-lanes and index-lane can never disagree on top-k near-ties.
        float v0 = -INFINITY, v1 = -INFINITY;
        int i0 = 0, i1 = 0;
#pragma unroll
        for (int e = 0; e < NUM_EXPERTS; ++e) {
            float v = acc[tt][e];
            v = dpp_add<0xB1>(v);   // quad_perm(1,0,3,2): xor1
            v = dpp_add<0x4E>(v);   // quad_perm(2,3,0,1): xor2
            v = dpp_add<0x141>(v);  // row_half_mirror: other quad within 8
            v += bb[e];
            // strict > keeps lowest index on ties, matching jax.lax.top_k
            if (v > v0) { v1 = v0; i1 = i0; v0 = v; i0 = e; }
            else if (v > v1) { v1 = v; i1 = e; }
        }
        const float e1 = expf(v1 - v0);
        const float w0 = 1.f / (1.f + e1);
        const float w1 = e1 * w0;

        // lanes l<2 of each group store weights (256B contiguous per tt per
        // wave); lane 2 stores the two indices.
        if (l < 2) {
            const int bd = l * 4;
            f4 v4;
            v4.x = (bd + 0 == i0) ? w0 : ((bd + 0 == i1) ? w1 : 0.f);
            v4.y = (bd + 1 == i0) ? w0 : ((bd + 1 == i1) ? w1 : 0.f);
            v4.z = (bd + 2 == i0) ? w0 : ((bd + 2 == i1) ? w1 : 0.f);
            v4.w = (bd + 3 == i0) ? w0 : ((bd + 3 == i1) ? w1 : 0.f);
            ((f4*)(out_w + (size_t)token * NUM_EXPERTS))[l] = v4;
        } else if (l == 2) {
            *(float2*)(out_idx + (size_t)token * TOP_K) =
                make_float2((float)i0, (float)i1);
        }
    }
}

extern "C" void kernel_launch(void* const* d_in, const int* in_sizes, int n_in,
                              void* d_out, int out_size, void* d_ws, size_t ws_size,
                              hipStream_t stream) {
    const float* x = (const float*)d_in[0];
    const float* W = (const float*)d_in[1];
    const float* b = (const float*)d_in[2];
    float* out = (float*)d_out;

    const int n_tokens = in_sizes[0] / D_MODEL;              // 32768
    float* out_w   = out;                                    // [n_tokens, 8]
    float* out_idx = out + (size_t)n_tokens * NUM_EXPERTS;   // [n_tokens, 2] as float

    const int grid = (n_tokens + TOKENS_PER_BLOCK - 1) / TOKENS_PER_BLOCK;  // 512
    gating_kernel<<<grid, 256, 0, stream>>>(x, W, b, out_w, out_idx, n_tokens);
}

// Round 3
// 445.984 us; speedup vs baseline: 1.1838x; 1.1838x over previous
//
#include <hip/hip_runtime.h>
#include <math.h>

#define D_MODEL 1024
#define NUM_EXPERTS 8
#define TOP_K 2
#define LANES_PER_TOKEN 8        // L: 8 lanes cooperate on one token
#define GROUPS_PER_WAVE 8        // 64 / L
#define TOKENS_PER_GROUP 2       // each W register feeds 2 tokens' FMAs
#define TOKENS_PER_WAVE (GROUPS_PER_WAVE * TOKENS_PER_GROUP)   // 16
#define WAVES_PER_BLOCK 4
#define TOKENS_PER_BLOCK (TOKENS_PER_WAVE * WAVES_PER_BLOCK)   // 64

typedef float f4 __attribute__((ext_vector_type(4)));

// One DPP-permute + add (pure VALU, no LDS pipe).
template<int CTRL>
__device__ __forceinline__ float dpp_add(float v) {
    int s = __builtin_amdgcn_update_dpp(0, __builtin_bit_cast(int, v),
                                        CTRL, 0xF, 0xF, true);
    return v + __builtin_bit_cast(float, s);
}

__device__ __forceinline__ float dot4(f4 a, f4 b) {
    return a.x * b.x + a.y * b.y + a.z * b.z + a.w * b.w;
}

// Round-0 structure (proven 186us total, ~28us kernel) + ONE change:
// TOKENS_PER_GROUP=2. Each ds_read_b128 of W (128B broadcast across the 8
// groups) now feeds 2 tokens' FMAs -> W-LDS reads per token drop 32 -> 16
// (~20.5 -> ~10.2 us/CU on the LDS pipe), leaving HBM (~21 us/CU) as the
// sole bottleneck. Round 2's chunk double-buffer (xa[2][2][8] = 128 VGPRs)
// caused a full spill (VGPR=256, 413MB scratch writes) -- removed. Single
// chunk buffer xa[2][8] = 64 VGPRs; HBM latency is hidden by TLP (8
// waves/CU, ~50KB/CU in flight > ~22KB Little's-law requirement) plus the
// chunk-0 loads issued before W staging.
__global__ __launch_bounds__(256) void gating_kernel(
    const float* __restrict__ x, const float* __restrict__ W,
    const float* __restrict__ b, float* __restrict__ out_w,
    float* __restrict__ out_idx, int n_tokens)
{
    __shared__ float Wlds[NUM_EXPERTS * D_MODEL];  // 32 KB

    const int wave = threadIdx.x >> 6;
    const int lane = threadIdx.x & 63;
    const int g = lane >> 3;
    const int l = lane & 7;
    const int base = blockIdx.x * TOKENS_PER_BLOCK + wave * TOKENS_PER_WAVE;
    const int t0 = base + g;       // tt=0: tokens base..base+7 across groups
    const int t1 = base + 8 + g;   // tt=1: tokens base+8..base+15

    // Clamp for OOB safety (stores are guarded); n_tokens%64==0 in practice.
    const int t0c = t0 < n_tokens ? t0 : 0;
    const int t1c = t1 < n_tokens ? t1 : 0;
    const f4* xg0 = (const f4*)x + (size_t)t0c * (D_MODEL / 4) + l;
    const f4* xg1 = (const f4*)x + (size_t)t1c * (D_MODEL / 4) + l;

    // Issue chunk-0 x loads BEFORE staging W: their ~900cy HBM latency hides
    // under the W stage + barrier.
    f4 xa[TOKENS_PER_GROUP][8];
#pragma unroll
    for (int kk = 0; kk < 8; ++kk) {
        xa[0][kk] = __builtin_nontemporal_load(xg0 + kk * 8);
        xa[1][kk] = __builtin_nontemporal_load(xg1 + kk * 8);
    }

    {   // stage W: 2048 float4 across 256 threads
        const f4* Wg = (const f4*)W;
        f4* Ws = (f4*)Wlds;
        const int tid = threadIdx.x;
#pragma unroll
        for (int i = 0; i < (NUM_EXPERTS * D_MODEL / 4) / 256; ++i)
            Ws[tid + i * 256] = Wg[tid + i * 256];
    }
    __syncthreads();

    const f4* Wl = (const f4*)Wlds + l;  // +e*256 + (c*8+kk)*8 per read

    float acc[TOKENS_PER_GROUP][NUM_EXPERTS];
#pragma unroll
    for (int tt = 0; tt < TOKENS_PER_GROUP; ++tt)
#pragma unroll
        for (int e = 0; e < NUM_EXPERTS; ++e) acc[tt][e] = 0.f;

#pragma unroll
    for (int c = 0; c < 4; ++c) {
        if (c > 0) {  // chunk 0 was loaded before the W stage
#pragma unroll
            for (int kk = 0; kk < 8; ++kk) {
                xa[0][kk] = __builtin_nontemporal_load(xg0 + (c * 8 + kk) * 8);
                xa[1][kk] = __builtin_nontemporal_load(xg1 + (c * 8 + kk) * 8);
            }
        }
#pragma unroll
        for (int e = 0; e < NUM_EXPERTS; ++e) {
            float s0 = acc[0][e];
            float s1 = acc[1][e];
#pragma unroll
            for (int kk = 0; kk < 8; ++kk) {
                const f4 wv = Wl[e * 256 + (c * 8 + kk) * 8];  // 128B/8 lanes,
                s0 += dot4(xa[0][kk], wv);                     // broadcast x8,
                s1 += dot4(xa[1][kk], wv);                     // reused 2 tokens
            }
            acc[0][e] = s0;
            acc[1][e] = s1;
        }
    }

    const f4 blo = ((const f4*)b)[0];
    const f4 bhi = ((const f4*)b)[1];
    const float bb[NUM_EXPERTS] = {blo.x, blo.y, blo.z, blo.w,
                                   bhi.x, bhi.y, bhi.z, bhi.w};

#pragma unroll
    for (int tt = 0; tt < TOKENS_PER_GROUP; ++tt) {
        const int token = base + tt * 8 + g;
        if (token >= n_tokens) continue;  // whole 8-lane group masks together

        // 8-lane group reduce: 3 DPP steps, XOR/mirror pairings -> all 8 lanes
        // get bit-identical sums (commutative adds, same grouping), so the
        // weight-lanes and index-lane can never disagree on top-k near-ties.
        float v0 = -INFINITY, v1 = -INFINITY;
        int i0 = 0, i1 = 0;
#pragma unroll
        for (int e = 0; e < NUM_EXPERTS; ++e) {
            float v = acc[tt][e];
            v = dpp_add<0xB1>(v);   // quad_perm(1,0,3,2): xor1
            v = dpp_add<0x4E>(v);   // quad_perm(2,3,0,1): xor2
            v = dpp_add<0x141>(v);  // row_half_mirror: other quad within 8
            v += bb[e];
            // strict > keeps lowest index on ties, matching jax.lax.top_k
            if (v > v0) { v1 = v0; i1 = i0; v0 = v; i0 = e; }
            else if (v > v1) { v1 = v; i1 = e; }
        }
        const float e1 = expf(v1 - v0);
        const float w0 = 1.f / (1.f + e1);
        const float w1 = e1 * w0;

        // lanes l<2 of each group store weights (256B contiguous per tt per
        // wave); lane 2 stores the two indices.
        if (l < 2) {
            const int bd = l * 4;
            f4 v4;
            v4.x = (bd + 0 == i0) ? w0 : ((bd + 0 == i1) ? w1 : 0.f);
            v4.y = (bd + 1 == i0) ? w0 : ((bd + 1 == i1) ? w1 : 0.f);
            v4.z = (bd + 2 == i0) ? w0 : ((bd + 2 == i1) ? w1 : 0.f);
            v4.w = (bd + 3 == i0) ? w0 : ((bd + 3 == i1) ? w1 : 0.f);
            ((f4*)(out_w + (size_t)token * NUM_EXPERTS))[l] = v4;
        } else if (l == 2) {
            *(float2*)(out_idx + (size_t)token * TOP_K) =
                make_float2((float)i0, (float)i1);
        }
    }
}

extern "C" void kernel_launch(void* const* d_in, const int* in_sizes, int n_in,
                              void* d_out, int out_size, void* d_ws, size_t ws_size,
                              hipStream_t stream) {
    const float* x = (const float*)d_in[0];
    const float* W = (const float*)d_in[1];
    const float* b = (const float*)d_in[2];
    float* out = (float*)d_out;

    const int n_tokens = in_sizes[0] / D_MODEL;              // 32768
    float* out_w   = out;                                    // [n_tokens, 8]
    float* out_idx = out + (size_t)n_tokens * NUM_EXPERTS;   // [n_tokens, 2] as float

    const int grid = (n_tokens + TOKENS_PER_BLOCK - 1) / TOKENS_PER_BLOCK;  // 512
    gating_kernel<<<grid, 256, 0, stream>>>(x, W, b, out_w, out_idx, n_tokens);
}

// Round 4
// 316.222 us; speedup vs baseline: 1.6696x; 1.4104x over previous
//
#include <hip/hip_runtime.h>
#include <math.h>

#define D_MODEL 1024
#define NUM_EXPERTS 8
#define TOP_K 2
#define LANES_PER_TOKEN 8        // L: 8 lanes cooperate on one token
#define GROUPS_PER_WAVE 8        // 64 / L
#define TOKENS_PER_GROUP 2       // each W register feeds 2 tokens' FMAs
#define TOKENS_PER_WAVE (GROUPS_PER_WAVE * TOKENS_PER_GROUP)   // 16
#define WAVES_PER_BLOCK 4
#define TOKENS_PER_BLOCK (TOKENS_PER_WAVE * WAVES_PER_BLOCK)   // 64

typedef float f4 __attribute__((ext_vector_type(4)));

// One DPP-permute + add (pure VALU, no LDS pipe).
template<int CTRL>
__device__ __forceinline__ float dpp_add(float v) {
    int s = __builtin_amdgcn_update_dpp(0, __builtin_bit_cast(int, v),
                                        CTRL, 0xF, 0xF, true);
    return v + __builtin_bit_cast(float, s);
}

__device__ __forceinline__ float dot4(f4 a, f4 b) {
    return a.x * b.x + a.y * b.y + a.z * b.z + a.w * b.w;
}

// TOKENS_PER_GROUP=2 halves W LDS reads/token (32->16). Rounds 2-3 spilled
// (VGPR=256, 412MB scratch): with the chunk loop fully unrolled the scheduler
// hoists all 4 chunks' x loads (4x64 VGPRs) above the compute. Fix:
// (1) #pragma unroll 1 on the chunk loop -- runtime trip count makes
//     cross-iteration load hoisting impossible;
// (2) __launch_bounds__(256,4) caps allocation at ~128 VGPR.
// Occupancy: 4 blocks/CU (128KB LDS), 16 waves/CU; per-chunk vmcnt wait is
// hidden by the 3 sibling waves per SIMD.
__global__ __launch_bounds__(256, 4) void gating_kernel(
    const float* __restrict__ x, const float* __restrict__ W,
    const float* __restrict__ b, float* __restrict__ out_w,
    float* __restrict__ out_idx, int n_tokens)
{
    __shared__ float Wlds[NUM_EXPERTS * D_MODEL];  // 32 KB

    const int wave = threadIdx.x >> 6;
    const int lane = threadIdx.x & 63;
    const int g = lane >> 3;
    const int l = lane & 7;
    const int base = blockIdx.x * TOKENS_PER_BLOCK + wave * TOKENS_PER_WAVE;
    const int t0 = base + g;       // tt=0: tokens base..base+7 across groups
    const int t1 = base + 8 + g;   // tt=1: tokens base+8..base+15

    // Clamp for OOB safety (stores are guarded); n_tokens%64==0 in practice.
    const int t0c = t0 < n_tokens ? t0 : 0;
    const int t1c = t1 < n_tokens ? t1 : 0;
    const f4* xg0 = (const f4*)x + (size_t)t0c * (D_MODEL / 4) + l;
    const f4* xg1 = (const f4*)x + (size_t)t1c * (D_MODEL / 4) + l;

    // Issue chunk-0 x loads BEFORE staging W: their HBM latency hides under
    // the W stage + barrier.
    f4 xa[TOKENS_PER_GROUP][8];
#pragma unroll
    for (int kk = 0; kk < 8; ++kk) {
        xa[0][kk] = __builtin_nontemporal_load(xg0 + kk * 8);
        xa[1][kk] = __builtin_nontemporal_load(xg1 + kk * 8);
    }

    {   // stage W: 2048 float4 across 256 threads
        const f4* Wg = (const f4*)W;
        f4* Ws = (f4*)Wlds;
        const int tid = threadIdx.x;
#pragma unroll
        for (int i = 0; i < (NUM_EXPERTS * D_MODEL / 4) / 256; ++i)
            Ws[tid + i * 256] = Wg[tid + i * 256];
    }
    __syncthreads();

    const f4* Wl = (const f4*)Wlds + l;

    float acc[TOKENS_PER_GROUP][NUM_EXPERTS];
#pragma unroll
    for (int tt = 0; tt < TOKENS_PER_GROUP; ++tt)
#pragma unroll
        for (int e = 0; e < NUM_EXPERTS; ++e) acc[tt][e] = 0.f;

#pragma unroll 1  // MUST stay unroll-1: full unroll => load hoisting => spill
    for (int c = 0; c < 4; ++c) {
        if (c > 0) {  // chunk 0 was loaded before the W stage
#pragma unroll
            for (int kk = 0; kk < 8; ++kk) {
                xa[0][kk] = __builtin_nontemporal_load(xg0 + (c * 8 + kk) * 8);
                xa[1][kk] = __builtin_nontemporal_load(xg1 + (c * 8 + kk) * 8);
            }
        }
        const f4* Wc = Wl + c * 64;  // runtime chunk base; e/kk offsets fold
#pragma unroll                       // into ds_read offset: immediates
        for (int e = 0; e < NUM_EXPERTS; ++e) {
            float s0 = acc[0][e];
            float s1 = acc[1][e];
#pragma unroll
            for (int kk = 0; kk < 8; ++kk) {
                const f4 wv = Wc[e * 256 + kk * 8];  // 128B/8 lanes, broadcast
                s0 += dot4(xa[0][kk], wv);           // x8 groups, reused for
                s1 += dot4(xa[1][kk], wv);           // 2 tokens
            }
            acc[0][e] = s0;
            acc[1][e] = s1;
        }
    }

    const f4 blo = ((const f4*)b)[0];
    const f4 bhi = ((const f4*)b)[1];
    const float bb[NUM_EXPERTS] = {blo.x, blo.y, blo.z, blo.w,
                                   bhi.x, bhi.y, bhi.z, bhi.w};

#pragma unroll
    for (int tt = 0; tt < TOKENS_PER_GROUP; ++tt) {
        const int token = base + tt * 8 + g;
        if (token >= n_tokens) continue;  // whole 8-lane group masks together

        // 8-lane group reduce: 3 DPP steps, XOR/mirror pairings -> all 8 lanes
        // get bit-identical sums (commutative adds, same grouping), so the
        // weight-lanes and index-lane can never disagree on top-k near-ties.
        float v0 = -INFINITY, v1 = -INFINITY;
        int i0 = 0, i1 = 0;
#pragma unroll
        for (int e = 0; e < NUM_EXPERTS; ++e) {
            float v = acc[tt][e];
            v = dpp_add<0xB1>(v);   // quad_perm(1,0,3,2): xor1
            v = dpp_add<0x4E>(v);   // quad_perm(2,3,0,1): xor2
            v = dpp_add<0x141>(v);  // row_half_mirror: other quad within 8
            v += bb[e];
            // strict > keeps lowest index on ties, matching jax.lax.top_k
            if (v > v0) { v1 = v0; i1 = i0; v0 = v; i0 = e; }
            else if (v > v1) { v1 = v; i1 = e; }
        }
        const float e1 = expf(v1 - v0);
        const float w0 = 1.f / (1.f + e1);
        const float w1 = e1 * w0;

        // lanes l<2 of each group store weights (256B contiguous per tt per
        // wave); lane 2 stores the two indices.
        if (l < 2) {
            const int bd = l * 4;
            f4 v4;
            v4.x = (bd + 0 == i0) ? w0 : ((bd + 0 == i1) ? w1 : 0.f);
            v4.y = (bd + 1 == i0) ? w0 : ((bd + 1 == i1) ? w1 : 0.f);
            v4.z = (bd + 2 == i0) ? w0 : ((bd + 2 == i1) ? w1 : 0.f);
            v4.w = (bd + 3 == i0) ? w0 : ((bd + 3 == i1) ? w1 : 0.f);
            ((f4*)(out_w + (size_t)token * NUM_EXPERTS))[l] = v4;
        } else if (l == 2) {
            *(float2*)(out_idx + (size_t)token * TOP_K) =
                make_float2((float)i0, (float)i1);
        }
    }
}

extern "C" void kernel_launch(void* const* d_in, const int* in_sizes, int n_in,
                              void* d_out, int out_size, void* d_ws, size_t ws_size,
                              hipStream_t stream) {
    const float* x = (const float*)d_in[0];
    const float* W = (const float*)d_in[1];
    const float* b = (const float*)d_in[2];
    float* out = (float*)d_out;

    const int n_tokens = in_sizes[0] / D_MODEL;              // 32768
    float* out_w   = out;                                    // [n_tokens, 8]
    float* out_idx = out + (size_t)n_tokens * NUM_EXPERTS;   // [n_tokens, 2] as float

    const int grid = (n_tokens + TOKENS_PER_BLOCK - 1) / TOKENS_PER_BLOCK;  // 512
    gating_kernel<<<grid, 256, 0, stream>>>(x, W, b, out_w, out_idx, n_tokens);
}

// Round 5
// 276.574 us; speedup vs baseline: 1.9089x; 1.1434x over previous
//
#include <hip/hip_runtime.h>
#include <math.h>

#define D_MODEL 1024
#define NUM_EXPERTS 8
#define TOP_K 2
#define TOKENS_PER_BLOCK 64   // one wave per block; lane = token

typedef float f4 __attribute__((ext_vector_type(4)));

// Layout: lane l owns token (base + l) entirely. W[e][d] is then wave-uniform
// -> compiler emits s_load (scalar K$ path), zero W traffic on LDS/VALU-adjacent
// pipes (round-0's bottleneck: 32 ds_read_b128 of W per token = 17us/CU, tied
// with HBM 21us/CU). LDS is used only to transpose x: stage [64 tok][64 floats]
// chunks with coalesced global loads (4x256B segments/instr), read back
// per-lane rows. LDS cost: 8 instr/token (4x less). Top-k/softmax fully
// lane-local: no cross-lane reduce, single lane decides weights AND indices.
//
// LDS swizzle (f4-slot granularity, row stride 64 floats = 256B == bank-period):
//   data (row r, col c) stored at slot c ^ (r>>3)
//   write instr j: lane -> row 4j+(lane>>4), holds col lane&15, slot (lane&15)^(j>>1)
//   read sub s:    lane reads row lane,      slot s^(lane>>3)
// Both patterns: 8 lanes per bank-quad = the b128 minimum (verified by
// (dword/4)%8 arithmetic: write quad = ((lane&15)^(j>>1))%8, read quad =
// (s^(lane>>3))%8 -- uniform over lanes).
__global__ __launch_bounds__(64) void gating_kernel(
    const float* __restrict__ x, const float* __restrict__ W,
    const float* __restrict__ b, float* __restrict__ out_w,
    float* __restrict__ out_idx, int n_tokens)
{
    __shared__ float xt[TOKENS_PER_BLOCK * 64];  // 16 KB, single buffer

    const int lane = threadIdx.x;        // 0..63
    const int base = blockIdx.x * TOKENS_PER_BLOCK;
    const int g = lane >> 3;             // 0..7, read-swizzle key
    const int h = lane >> 4;             // 0..3, staging row-within-quad
    const int q16 = lane & 15;           // staging col (f4 units)

    // Staging source offsets (f4 units): instr j covers rows 4j+h, 4 x 256B
    // contiguous segments per instruction.
    int rowoff[16];
#pragma unroll
    for (int j = 0; j < 16; ++j) {
        int r = base + 4 * j + h;
        if (r >= n_tokens) r = n_tokens - 1;  // clamp; stores are guarded
        rowoff[j] = r * (D_MODEL / 4) + q16;
    }

    f4* xtf = (f4*)xt;
    const f4* xg = (const f4*)x;
    const f4* Wf = (const f4*)W;

    // Precompute LDS addresses (f4-unit indices) once; reused every chunk.
    int wslot[16];
#pragma unroll
    for (int j = 0; j < 16; ++j)
        wslot[j] = (4 * j + h) * 16 + (q16 ^ (j >> 1));
    int rslot[16];
#pragma unroll
    for (int s = 0; s < 16; ++s)
        rslot[s] = lane * 16 + (s ^ g);

    float acc[NUM_EXPERTS];
#pragma unroll
    for (int e = 0; e < NUM_EXPERTS; ++e) acc[e] = 0.f;

    // Prologue: chunk 0 loads into registers.
    f4 xa[16];
#pragma unroll
    for (int j = 0; j < 16; ++j)
        xa[j] = __builtin_nontemporal_load(xg + rowoff[j]);

#pragma unroll 1  // MUST stay unroll-1: full unroll lets the scheduler hoist
    for (int c = 0; c < 16; ++c) {  // all chunks' loads -> spill (rounds 2-4)
        // Commit chunk c (in xa) to LDS. Waits vmcnt for chunk c only --
        // chunk c+1's loads are not yet issued.
#pragma unroll
        for (int j = 0; j < 16; ++j)
            xtf[wslot[j]] = xa[j];

        // Issue chunk c+1 loads. Anti-dependency on xa keeps these after the
        // ds_writes; their latency overlaps the compute below.
        if (c < 15) {
#pragma unroll
            for (int j = 0; j < 16; ++j)
                xa[j] = __builtin_nontemporal_load(
                    xg + rowoff[j] + (c + 1) * 16);
        }

        // Compute chunk c: 16 subs x 8 experts. W index is wave-uniform
        // (e, c, s all uniform) -> s_load_dwordx4 on the scalar path.
#pragma unroll
        for (int s = 0; s < 16; ++s) {
            const f4 xv = xtf[rslot[s]];
#pragma unroll
            for (int e = 0; e < NUM_EXPERTS; ++e) {
                const f4 wv = Wf[e * 256 + c * 16 + s];
                acc[e] += xv.x * wv.x + xv.y * wv.y +
                          xv.z * wv.z + xv.w * wv.w;
            }
        }
    }

    // Bias (uniform -> SGPRs), then per-lane top-2 + softmax. All decisions in
    // ONE lane: no cross-lane agreement concerns at ties.
    const f4 bl = ((const f4*)b)[0];
    const f4 bh = ((const f4*)b)[1];
    const float lg[NUM_EXPERTS] = {
        acc[0] + bl.x, acc[1] + bl.y, acc[2] + bl.z, acc[3] + bl.w,
        acc[4] + bh.x, acc[5] + bh.y, acc[6] + bh.z, acc[7] + bh.w};

    float v0 = -INFINITY, v1 = -INFINITY;
    int i0 = 0, i1 = 0;
#pragma unroll
    for (int e = 0; e < NUM_EXPERTS; ++e) {
        const float v = lg[e];
        // strict > keeps lowest index on ties, matching jax.lax.top_k
        if (v > v0) { v1 = v0; i1 = i0; v0 = v; i0 = e; }
        else if (v > v1) { v1 = v; i1 = e; }
    }
    const float e1 = expf(v1 - v0);
    const float w0 = 1.f / (1.f + e1);
    const float w1 = e1 * w0;

    const int token = base + lane;
    if (token < n_tokens) {
        f4 wlo, whi;
        wlo.x = (0 == i0) ? w0 : ((0 == i1) ? w1 : 0.f);
        wlo.y = (1 == i0) ? w0 : ((1 == i1) ? w1 : 0.f);
        wlo.z = (2 == i0) ? w0 : ((2 == i1) ? w1 : 0.f);
        wlo.w = (3 == i0) ? w0 : ((3 == i1) ? w1 : 0.f);
        whi.x = (4 == i0) ? w0 : ((4 == i1) ? w1 : 0.f);
        whi.y = (5 == i0) ? w0 : ((5 == i1) ? w1 : 0.f);
        whi.z = (6 == i0) ? w0 : ((6 == i1) ? w1 : 0.f);
        whi.w = (7 == i0) ? w0 : ((7 == i1) ? w1 : 0.f);
        f4* po = (f4*)(out_w + (size_t)token * NUM_EXPERTS);
        po[0] = wlo;
        po[1] = whi;
        *(float2*)(out_idx + (size_t)token * TOP_K) =
            make_float2((float)i0, (float)i1);
    }
}

extern "C" void kernel_launch(void* const* d_in, const int* in_sizes, int n_in,
                              void* d_out, int out_size, void* d_ws, size_t ws_size,
                              hipStream_t stream) {
    const float* x = (const float*)d_in[0];
    const float* W = (const float*)d_in[1];
    const float* b = (const float*)d_in[2];
    float* out = (float*)d_out;

    const int n_tokens = in_sizes[0] / D_MODEL;              // 32768
    float* out_w   = out;                                    // [n_tokens, 8]
    float* out_idx = out + (size_t)n_tokens * NUM_EXPERTS;   // [n_tokens, 2] as float

    const int grid = (n_tokens + TOKENS_PER_BLOCK - 1) / TOKENS_PER_BLOCK;  // 512
    gating_kernel<<<grid, 64, 0, stream>>>(x, W, b, out_w, out_idx, n_tokens);
}

// Round 6
// 197.861 us; speedup vs baseline: 2.6683x; 1.3978x over previous
//
#include <hip/hip_runtime.h>
#include <math.h>

#define D_MODEL 1024
#define NUM_EXPERTS 8
#define TOP_K 2
#define LANES_PER_TOKEN 8                          // L: 8 lanes cooperate on one token
#define TOKENS_PER_WAVE 8                          // T = 64/L
#define WAVES_PER_BLOCK 4
#define TOKENS_PER_BLOCK (TOKENS_PER_WAVE * WAVES_PER_BLOCK)  // 32

typedef float f4 __attribute__((ext_vector_type(4)));

// Proven round-0 structure (185.5/186.0 us total, gating ~28 us, 20 waves/CU).
// ONE change vs round 0: x loads are PLAIN (not nontemporal). Measured in
// round 5: x (134 MB < 256 MB Infinity Cache) stays ~50% L3-resident across
// bench iterations even WITH the nt hint (FETCH_SIZE=66 MB for a 134 MB read);
// nt marks lines evict-first and limits retention. Plain loads let L3 keep
// more of x -> less HBM time for the ~memory-bound gating kernel.
// (Rounds 1-5 post-mortems: W-in-VGPR = occupancy/latency loss; 2-token
// W-reuse = allocator-hostile, spills; lane=token = 2 waves/CU latency death.
// Do not restructure this kernel without counter evidence.)
__global__ __launch_bounds__(256) void gating_kernel(
    const float* __restrict__ x, const float* __restrict__ W,
    const float* __restrict__ b, float* __restrict__ out_w,
    float* __restrict__ out_idx, int n_tokens)
{
    __shared__ float Wlds[NUM_EXPERTS * D_MODEL];  // 32 KB -> 5 blocks/CU max

    {   // stage W: 2048 float4 across 256 threads
        const f4* Wg = (const f4*)W;
        f4* Ws = (f4*)Wlds;
        const int tid = threadIdx.x;
#pragma unroll
        for (int i = 0; i < (NUM_EXPERTS * D_MODEL / 4) / 256; ++i)
            Ws[tid + i * 256] = Wg[tid + i * 256];
    }
    __syncthreads();

    const int wave = threadIdx.x >> 6;
    const int lane = threadIdx.x & 63;
    const int g = lane >> 3;
    const int l = lane & 7;
    const int token = blockIdx.x * TOKENS_PER_BLOCK + wave * TOKENS_PER_WAVE + g;
    if (token >= n_tokens) return;

    const f4* xg = (const f4*)x + (size_t)token * (D_MODEL / 4) + l;  // +k*8 per chunk
    const f4* Wl = (const f4*)Wlds + l;                               // +e*256 + k*8

    float acc[NUM_EXPERTS];
#pragma unroll
    for (int e = 0; e < NUM_EXPERTS; ++e) acc[e] = 0.f;

#pragma unroll
    for (int c = 0; c < 4; ++c) {
        f4 xa[8];
#pragma unroll
        for (int kk = 0; kk < 8; ++kk)
            xa[kk] = xg[(c * 8 + kk) * 8];   // plain load: keep x L3-resident
#pragma unroll
        for (int e = 0; e < NUM_EXPERTS; ++e) {
            float s = acc[e];
#pragma unroll
            for (int kk = 0; kk < 8; ++kk) {
                const f4 wv = Wl[e * 256 + (c * 8 + kk) * 8];
                s += xa[kk].x * wv.x + xa[kk].y * wv.y +
                     xa[kk].z * wv.z + xa[kk].w * wv.w;
            }
            acc[e] = s;
        }
    }

    // Reduce across the 8 lanes of the group: 3 butterfly steps per expert.
#pragma unroll
    for (int e = 0; e < NUM_EXPERTS; ++e) {
        float v = acc[e];
        v += __shfl_xor(v, 1, 64);
        v += __shfl_xor(v, 2, 64);
        v += __shfl_xor(v, 4, 64);
        acc[e] = v + b[e];
    }

    // Every lane of the group holds the full logits; compute top-2 + softmax.
    float v0 = -INFINITY, v1 = -INFINITY;
    int i0 = 0, i1 = 0;
#pragma unroll
    for (int e = 0; e < NUM_EXPERTS; ++e) {
        float v = acc[e];
        // strict > keeps lowest index on ties, matching jax.lax.top_k
        if (v > v0) { v1 = v0; i1 = i0; v0 = v; i0 = e; }
        else if (v > v1) { v1 = v; i1 = e; }
    }
    const float e1 = expf(v1 - v0);
    const float w0 = 1.f / (1.f + e1);
    const float w1 = e1 * w0;

    // Writes spread over 3 lanes of each group; weight stores coalesce to
    // 256B-contiguous runs per wave.
    if (l < 2) {
        const int base = l * 4;
        f4 v4;
        v4.x = (base + 0 == i0) ? w0 : ((base + 0 == i1) ? w1 : 0.f);
        v4.y = (base + 1 == i0) ? w0 : ((base + 1 == i1) ? w1 : 0.f);
        v4.z = (base + 2 == i0) ? w0 : ((base + 2 == i1) ? w1 : 0.f);
        v4.w = (base + 3 == i0) ? w0 : ((base + 3 == i1) ? w1 : 0.f);
        ((f4*)(out_w + (size_t)token * NUM_EXPERTS))[l] = v4;
    } else if (l == 2) {
        *(float2*)(out_idx + (size_t)token * TOP_K) =
            make_float2((float)i0, (float)i1);
    }
}

extern "C" void kernel_launch(void* const* d_in, const int* in_sizes, int n_in,
                              void* d_out, int out_size, void* d_ws, size_t ws_size,
                              hipStream_t stream) {
    const float* x = (const float*)d_in[0];
    const float* W = (const float*)d_in[1];
    const float* b = (const float*)d_in[2];
    float* out = (float*)d_out;

    const int n_tokens = in_sizes[0] / D_MODEL;              // 32768
    float* out_w   = out;                                    // [n_tokens, 8]
    float* out_idx = out + (size_t)n_tokens * NUM_EXPERTS;   // [n_tokens, 2] as float

    const int grid = (n_tokens + TOKENS_PER_BLOCK - 1) / TOKENS_PER_BLOCK;  // 1024
    gating_kernel<<<grid, 256, 0, stream>>>(x, W, b, out_w, out_idx, n_tokens);
}

// Round 7
// 185.340 us; speedup vs baseline: 2.8486x; 1.0676x over previous
//
#include <hip/hip_runtime.h>
#include <math.h>

#define D_MODEL 1024
#define NUM_EXPERTS 8
#define TOP_K 2
#define LANES_PER_TOKEN 8                          // L: 8 lanes cooperate on one token
#define TOKENS_PER_WAVE 8                          // T = 64/L
#define WAVES_PER_BLOCK 4
#define TOKENS_PER_BLOCK (TOKENS_PER_WAVE * WAVES_PER_BLOCK)  // 32

typedef float f4 __attribute__((ext_vector_type(4)));

// PROVEN BEST (round 0: 185.5/186.0 us total; gating ~28 us, 20 waves/CU).
// Byte-exact revert after 6 structural experiments all regressed:
//   r1 W-in-VGPR wave/token:   191us (occupancy 8 waves/CU + serial 64-lane reduce)
//   r2/r3 2-token W-reuse:     528/446us (allocator spill: VGPR=256, 400MB scratch)
//   r4/r5 lane=token W-scalar: 316/277us (2 waves/CU latency + LDS bank conflicts)
//   r6 plain (non-nt) x loads: 198us (L2/L3 pollution; nt evict-first WINS here)
// Mechanism ledger: LDS pipe ~20.5us/CU (32 ds_read_b128 of W per token) is
// tied with HBM ~21.8us/CU; they overlap to ~28us. Every structure that cuts
// LDS traffic costs more in occupancy/registers than it saves. Do not
// restructure without new counter evidence.
__global__ __launch_bounds__(256) void gating_kernel(
    const float* __restrict__ x, const float* __restrict__ W,
    const float* __restrict__ b, float* __restrict__ out_w,
    float* __restrict__ out_idx, int n_tokens)
{
    __shared__ float Wlds[NUM_EXPERTS * D_MODEL];  // 32 KB -> 5 blocks/CU max

    {   // stage W: 2048 float4 across 256 threads
        const f4* Wg = (const f4*)W;
        f4* Ws = (f4*)Wlds;
        const int tid = threadIdx.x;
#pragma unroll
        for (int i = 0; i < (NUM_EXPERTS * D_MODEL / 4) / 256; ++i)
            Ws[tid + i * 256] = Wg[tid + i * 256];
    }
    __syncthreads();

    const int wave = threadIdx.x >> 6;
    const int lane = threadIdx.x & 63;
    const int g = lane >> 3;
    const int l = lane & 7;
    const int token = blockIdx.x * TOKENS_PER_BLOCK + wave * TOKENS_PER_WAVE + g;
    if (token >= n_tokens) return;

    const f4* xg = (const f4*)x + (size_t)token * (D_MODEL / 4) + l;  // +k*8 per chunk
    const f4* Wl = (const f4*)Wlds + l;                               // +e*256 + k*8

    float acc[NUM_EXPERTS];
#pragma unroll
    for (int e = 0; e < NUM_EXPERTS; ++e) acc[e] = 0.f;

#pragma unroll
    for (int c = 0; c < 4; ++c) {
        f4 xa[8];
#pragma unroll
        for (int kk = 0; kk < 8; ++kk)
            xa[kk] = __builtin_nontemporal_load(xg + (c * 8 + kk) * 8);
#pragma unroll
        for (int e = 0; e < NUM_EXPERTS; ++e) {
            float s = acc[e];
#pragma unroll
            for (int kk = 0; kk < 8; ++kk) {
                const f4 wv = Wl[e * 256 + (c * 8 + kk) * 8];
                s += xa[kk].x * wv.x + xa[kk].y * wv.y +
                     xa[kk].z * wv.z + xa[kk].w * wv.w;
            }
            acc[e] = s;
        }
    }

    // Reduce across the 8 lanes of the group: 3 butterfly steps per expert.
#pragma unroll
    for (int e = 0; e < NUM_EXPERTS; ++e) {
        float v = acc[e];
        v += __shfl_xor(v, 1, 64);
        v += __shfl_xor(v, 2, 64);
        v += __shfl_xor(v, 4, 64);
        acc[e] = v + b[e];
    }

    // Every lane of the group holds the full logits; compute top-2 + softmax.
    float v0 = -INFINITY, v1 = -INFINITY;
    int i0 = 0, i1 = 0;
#pragma unroll
    for (int e = 0; e < NUM_EXPERTS; ++e) {
        float v = acc[e];
        // strict > keeps lowest index on ties, matching jax.lax.top_k
        if (v > v0) { v1 = v0; i1 = i0; v0 = v; i0 = e; }
        else if (v > v1) { v1 = v; i1 = e; }
    }
    const float e1 = expf(v1 - v0);
    const float w0 = 1.f / (1.f + e1);
    const float w1 = e1 * w0;

    // Writes spread over 3 lanes of each group; weight stores coalesce to
    // 256B-contiguous runs per wave.
    if (l < 2) {
        const int base = l * 4;
        f4 v4;
        v4.x = (base + 0 == i0) ? w0 : ((base + 0 == i1) ? w1 : 0.f);
        v4.y = (base + 1 == i0) ? w0 : ((base + 1 == i1) ? w1 : 0.f);
        v4.z = (base + 2 == i0) ? w0 : ((base + 2 == i1) ? w1 : 0.f);
        v4.w = (base + 3 == i0) ? w0 : ((base + 3 == i1) ? w1 : 0.f);
        ((f4*)(out_w + (size_t)token * NUM_EXPERTS))[l] = v4;
    } else if (l == 2) {
        *(float2*)(out_idx + (size_t)token * TOP_K) =
            make_float2((float)i0, (float)i1);
    }
}

extern "C" void kernel_launch(void* const* d_in, const int* in_sizes, int n_in,
                              void* d_out, int out_size, void* d_ws, size_t ws_size,
                              hipStream_t stream) {
    const float* x = (const float*)d_in[0];
    const float* W = (const float*)d_in[1];
    const float* b = (const float*)d_in[2];
    float* out = (float*)d_out;

    const int n_tokens = in_sizes[0] / D_MODEL;              // 32768
    float* out_w   = out;                                    // [n_tokens, 8]
    float* out_idx = out + (size_t)n_tokens * NUM_EXPERTS;   // [n_tokens, 2] as float

    const int grid = (n_tokens + TOKENS_PER_BLOCK - 1) / TOKENS_PER_BLOCK;  // 1024
    gating_kernel<<<grid, 256, 0, stream>>>(x, W, b, out_w, out_idx, n_tokens);
}